// Round 8
// baseline (206.531 us; speedup 1.0000x reference)
//
#include <hip/hip_runtime.h>
#include <hip/hip_bf16.h>
#include <stdint.h>

// Problem constants (fixed by reference spec; dtypes f32/int32 verified over
// rounds 3-7 — bit-stable outputs; bounds-clamps retained as the safety net)
#define N_NODES   10000
#define D_FEAT    256
#define E_EDGES   320000
#define ROW_WORDS 313     // ceil(10000/32) bitmap words per row
#define ROW_STRIDE 320    // padded words per bitmap row (1280 B)
#define LIST_CAP  1024    // per-wave neighbor list capacity (deg ~ Poisson(64))

typedef __attribute__((ext_vector_type(4))) float float4v;  // 4 x f32

__device__ __forceinline__ uint16_t f2bf(float f) {   // RNE, finite inputs
    union { float f; uint32_t u; } v; v.f = f;
    uint32_t r = v.u + 0x7fffu + ((v.u >> 16) & 1u);
    return (uint16_t)(r >> 16);
}
__device__ __forceinline__ float lo16(uint32_t u) {   // bf16 in low half -> f32
    union { uint32_t u; float f; } v; v.u = u << 16; return v.f;
}
__device__ __forceinline__ float hi16(uint32_t u) {   // bf16 in high half -> f32
    union { uint32_t u; float f; } v; v.u = u & 0xffff0000u; return v.f;
}

// ===========================================================================
// PRIMARY PLAN (ws >= ~18 MB): bitmap + fused degree + bf16-prescaled gather
// ===========================================================================

// ---------------------------------------------------------------------------
// P1: scatter edges into bitmap AND count unique neighbors in one pass.
// atomicOr returns the old word: bit-was-clear <=> this thread is the unique
// setter <=> increment deg. Exact set semantics, duplicates & self-edges OK.
// ---------------------------------------------------------------------------
__global__ void scatter_deg(const int* __restrict__ ei,
                            uint32_t* __restrict__ bitmap,
                            uint32_t* __restrict__ deg) {
    int e = blockIdx.x * blockDim.x + threadIdx.x;
    if (e >= E_EDGES) return;
    int s = ei[e], d = ei[E_EDGES + e];
    if ((uint32_t)s >= N_NODES || (uint32_t)d >= N_NODES) return;
    uint32_t o1 = atomicOr(&bitmap[(size_t)s * ROW_STRIDE + (d >> 5)], 1u << (d & 31));
    if (!((o1 >> (d & 31)) & 1u)) atomicAdd(&deg[s], 1u);
    uint32_t o2 = atomicOr(&bitmap[(size_t)d * ROW_STRIDE + (s >> 5)], 1u << (s & 31));
    if (!((o2 >> (s & 31)) & 1u)) atomicAdd(&deg[d], 1u);
}

// ---------------------------------------------------------------------------
// P2: dinv_i = 1/sqrt(deg_i + 1);  xs_i = bf16(dinv_i * x_i)  [5 MB table].
// One wave per row (4 rows / 256-thr block); 16B-coalesced read, 8B write.
// The 5 MB bf16 table ~ fits per-XCD L2 (4 MiB) -> round-7's 135 MB of
// L2-miss gather traffic should mostly collapse to L2 hits.
// ---------------------------------------------------------------------------
__global__ void __launch_bounds__(256)
scale_cast(const uint32_t* __restrict__ deg, const float* __restrict__ x,
           float* __restrict__ dinv, uint16_t* __restrict__ xs) {
    int wv = threadIdx.x >> 6, lane = threadIdx.x & 63;
    int i = blockIdx.x * 4 + wv;
    float di = 1.0f / sqrtf((float)(deg[i] + 1u));
    if (lane == 0) dinv[i] = di;
    float4v v = *(const float4v*)(x + (size_t)i * D_FEAT + lane * 4);
    uint2 o;
    o.x = (uint32_t)f2bf(di * v[0]) | ((uint32_t)f2bf(di * v[1]) << 16);
    o.y = (uint32_t)f2bf(di * v[2]) | ((uint32_t)f2bf(di * v[3]) << 16);
    *(uint2*)(xs + (size_t)i * D_FEAT + lane * 4) = o;
}

// ---------------------------------------------------------------------------
// P3: aggregation. One wave per row (4 rows / 256-thr block).
// Phase 1 (r7-verified): bitmap row -> wave-local LDS index list, shfl scan,
//   no barriers (wave-synchronous LDS).
// Phase 2: gather PRESCALED bf16 rows, 4 independent accumulator sets so 4
//   512B gathers are in flight. Self term = xs_i added unconditionally:
//   self-bit (diag 1) + this term reproduces adj+I's diag of 1 or 2 exactly.
// out_i(f32, into d_out) = dinv_i * ( sum_{j in bits(row_i)} xs_j + xs_i )
// ---------------------------------------------------------------------------
__global__ void __launch_bounds__(256)
spmm_xs(const uint32_t* __restrict__ bitmap, const float* __restrict__ dinv,
        const uint16_t* __restrict__ xs, float* __restrict__ agg) {
    __shared__ __align__(16) uint32_t lists[4][LIST_CAP];   // 16 KB
    int wv = threadIdx.x >> 6, lane = threadIdx.x & 63;
    int i = blockIdx.x * 4 + wv;
    uint32_t* list = lists[wv];
    const uint32_t* rb = bitmap + (size_t)i * ROW_STRIDE;

    // ---- Phase 1: bitmap -> index list ----
    uint32_t wbits[5]; int tot = 0;
    #pragma unroll
    for (int k = 0; k < 5; k++) {
        int w = lane + 64 * k;
        uint32_t b = (w < ROW_WORDS) ? rb[w] : 0u;
        wbits[k] = b;
        tot += __popc(b);
    }
    int incl = tot;
    #pragma unroll
    for (int off = 1; off < 64; off <<= 1) {
        int v = __shfl_up(incl, off, 64);
        if (lane >= off) incl += v;
    }
    uint32_t p = (uint32_t)(incl - tot);
    uint32_t deg = (uint32_t)__shfl(incl, 63, 64);
    #pragma unroll
    for (int k = 0; k < 5; k++) {
        uint32_t bits = wbits[k];
        uint32_t base = (uint32_t)(lane + 64 * k) << 5;
        while (bits) {
            if (p < LIST_CAP) list[p] = base + (uint32_t)__builtin_ctz(bits);
            p++;
            bits &= bits - 1;
        }
    }
    if (deg > LIST_CAP) deg = LIST_CAP;          // safety clamp (never expected)

    // ---- Phase 2: gather bf16 prescaled rows ----
    float4v z = {0.f, 0.f, 0.f, 0.f};
    float4v acc0 = z, acc1 = z, acc2 = z, acc3 = z;
    size_t ch = (size_t)lane * 4;
    uint32_t t4 = deg & ~3u;
    for (uint32_t t = 0; t < t4; t += 4) {
        uint4 jv = *(const uint4*)&list[t];      // LDS broadcast (same addr)
        uint2 g0 = *(const uint2*)(xs + (size_t)jv.x * D_FEAT + ch);
        uint2 g1 = *(const uint2*)(xs + (size_t)jv.y * D_FEAT + ch);
        uint2 g2 = *(const uint2*)(xs + (size_t)jv.z * D_FEAT + ch);
        uint2 g3 = *(const uint2*)(xs + (size_t)jv.w * D_FEAT + ch);
        acc0[0] += lo16(g0.x); acc0[1] += hi16(g0.x); acc0[2] += lo16(g0.y); acc0[3] += hi16(g0.y);
        acc1[0] += lo16(g1.x); acc1[1] += hi16(g1.x); acc1[2] += lo16(g1.y); acc1[3] += hi16(g1.y);
        acc2[0] += lo16(g2.x); acc2[1] += hi16(g2.x); acc2[2] += lo16(g2.y); acc2[3] += hi16(g2.y);
        acc3[0] += lo16(g3.x); acc3[1] += hi16(g3.x); acc3[2] += lo16(g3.y); acc3[3] += hi16(g3.y);
    }
    for (uint32_t t = t4; t < deg; t++) {
        uint32_t j = list[t];
        uint2 g = *(const uint2*)(xs + (size_t)j * D_FEAT + ch);
        acc0[0] += lo16(g.x); acc0[1] += hi16(g.x); acc0[2] += lo16(g.y); acc0[3] += hi16(g.y);
    }
    // self term (+I): xs_i once more
    uint2 gs = *(const uint2*)(xs + (size_t)i * D_FEAT + ch);
    acc1[0] += lo16(gs.x); acc1[1] += hi16(gs.x); acc1[2] += lo16(gs.y); acc1[3] += hi16(gs.y);

    float di = dinv[i];
    float4v acc = (acc0 + acc1) + (acc2 + acc3);
    *(float4v*)(agg + (size_t)i * D_FEAT + ch) = di * acc;
}

// ===========================================================================
// FALLBACK PLAN (r7-proven, needs ~12.85 MB): bitmap + popc + f32 gather
// ===========================================================================

__global__ void scatter_edges_fb(const int* __restrict__ ei,
                                 uint32_t* __restrict__ bitmap) {
    int e = blockIdx.x * blockDim.x + threadIdx.x;
    if (e >= E_EDGES) return;
    int s = ei[e], d = ei[E_EDGES + e];
    if ((uint32_t)s >= N_NODES || (uint32_t)d >= N_NODES) return;
    atomicOr(&bitmap[(size_t)s * ROW_STRIDE + (d >> 5)], 1u << (d & 31));
    atomicOr(&bitmap[(size_t)d * ROW_STRIDE + (s >> 5)], 1u << (s & 31));
}

__global__ void __launch_bounds__(256)
popc_dinv(const uint32_t* __restrict__ bitmap, float* __restrict__ dinv) {
    int wv = threadIdx.x >> 6, lane = threadIdx.x & 63;
    int i = blockIdx.x * 4 + wv;
    const uint32_t* rb = bitmap + (size_t)i * ROW_STRIDE;
    int pop = 0;
    #pragma unroll
    for (int k = 0; k < 5; k++) {
        int w = lane + 64 * k;
        if (w < ROW_WORDS) pop += __popc(rb[w]);
    }
    #pragma unroll
    for (int off = 32; off > 0; off >>= 1) pop += __shfl_xor(pop, off, 64);
    if (lane == 0) dinv[i] = 1.0f / sqrtf((float)(pop + 1));
}

__global__ void __launch_bounds__(256)
spmm_bitmap_fb(const uint32_t* __restrict__ bitmap, const float* __restrict__ dinv,
               const float* __restrict__ xf, float* __restrict__ agg) {
    __shared__ __align__(16) uint32_t lists[4][LIST_CAP];
    int wv = threadIdx.x >> 6, lane = threadIdx.x & 63;
    int i = blockIdx.x * 4 + wv;
    uint32_t* list = lists[wv];
    const uint32_t* rb = bitmap + (size_t)i * ROW_STRIDE;

    uint32_t wbits[5]; int tot = 0;
    #pragma unroll
    for (int k = 0; k < 5; k++) {
        int w = lane + 64 * k;
        uint32_t b = (w < ROW_WORDS) ? rb[w] : 0u;
        wbits[k] = b;
        tot += __popc(b);
    }
    int incl = tot;
    #pragma unroll
    for (int off = 1; off < 64; off <<= 1) {
        int v = __shfl_up(incl, off, 64);
        if (lane >= off) incl += v;
    }
    uint32_t p = (uint32_t)(incl - tot);
    uint32_t deg = (uint32_t)__shfl(incl, 63, 64);
    #pragma unroll
    for (int k = 0; k < 5; k++) {
        uint32_t bits = wbits[k];
        uint32_t base = (uint32_t)(lane + 64 * k) << 5;
        while (bits) {
            if (p < LIST_CAP) list[p] = base + (uint32_t)__builtin_ctz(bits);
            p++;
            bits &= bits - 1;
        }
    }
    if (deg > LIST_CAP) deg = LIST_CAP;

    float di = dinv[i];
    float4v z = {0.f, 0.f, 0.f, 0.f};
    float4v acc0 = z, acc1 = z, acc2 = z, acc3 = z;
    float4v sv = *(const float4v*)(xf + (size_t)i * D_FEAT + lane * 4);
    uint32_t t4 = deg & ~3u;
    for (uint32_t t = 0; t < t4; t += 4) {
        uint4 jv = *(const uint4*)&list[t];
        float d0 = dinv[jv.x], d1 = dinv[jv.y], d2 = dinv[jv.z], d3 = dinv[jv.w];
        float4v v0 = *(const float4v*)(xf + (size_t)jv.x * D_FEAT + lane * 4);
        float4v v1 = *(const float4v*)(xf + (size_t)jv.y * D_FEAT + lane * 4);
        float4v v2 = *(const float4v*)(xf + (size_t)jv.z * D_FEAT + lane * 4);
        float4v v3 = *(const float4v*)(xf + (size_t)jv.w * D_FEAT + lane * 4);
        acc0 += d0 * v0; acc1 += d1 * v1; acc2 += d2 * v2; acc3 += d3 * v3;
    }
    for (uint32_t t = t4; t < deg; t++) {
        uint32_t j = list[t];
        acc0 += dinv[j] * (*(const float4v*)(xf + (size_t)j * D_FEAT + lane * 4));
    }
    float4v acc = (acc0 + acc1) + (acc2 + acc3) + di * sv;
    *(float4v*)(agg + (size_t)i * D_FEAT + lane * 4) = di * acc;
}

// ===========================================================================
// Shared epilogue GEMM: out[band,:] = agg[band,:] @ W, in place on d_out.
// Round-8 change: ds_read_b128 A-tile reads (4096 -> 1024 LDS instrs/thread;
// r7's scalar version was LDS-issue-bound at ~24 us).
// ===========================================================================
__global__ void __launch_bounds__(256)
gemm_valu(float* __restrict__ io, const float* __restrict__ wf) {
    __shared__ __align__(16) float a_lds[16 * D_FEAT];
    int c = threadIdx.x;
    int r0 = blockIdx.x * 16;
    for (int idx = c; idx < 16 * D_FEAT; idx += 256)
        a_lds[idx] = io[(size_t)r0 * D_FEAT + idx];
    __syncthreads();

    float acc[16];
    #pragma unroll
    for (int r = 0; r < 16; r++) acc[r] = 0.f;

    for (int k0 = 0; k0 < D_FEAT; k0 += 4) {
        float w0 = wf[(size_t)(k0 + 0) * D_FEAT + c];
        float w1 = wf[(size_t)(k0 + 1) * D_FEAT + c];
        float w2 = wf[(size_t)(k0 + 2) * D_FEAT + c];
        float w3 = wf[(size_t)(k0 + 3) * D_FEAT + c];
        #pragma unroll
        for (int r = 0; r < 16; r++) {
            float4v av = *(const float4v*)&a_lds[r * D_FEAT + k0];  // b128 bcast
            acc[r] = fmaf(av[3], w3, fmaf(av[2], w2,
                     fmaf(av[1], w1, fmaf(av[0], w0, acc[r]))));
        }
    }
    #pragma unroll
    for (int r = 0; r < 16; r++)
        io[(size_t)(r0 + r) * D_FEAT + c] = acc[r];
}

// ---------------------------------------------------------------------------
extern "C" void kernel_launch(void* const* d_in, const int* in_sizes, int n_in,
                              void* d_out, int out_size, void* d_ws, size_t ws_size,
                              hipStream_t stream) {
    const float* x  = (const float*)d_in[0];     // f32 [N, 256]
    const int*   ei = (const int*)d_in[1];       // int32 [2, E]
    const float* w  = (const float*)d_in[2];     // f32 [256, 256]
    float* out = (float*)d_out;                  // f32 [N, 256]
    uint8_t* ws = (uint8_t*)d_ws;

    // Primary layout:
    //   bitmap @ 0          : 12,800,000 B
    //   deg    @ 12,800,000 :     40,000 B   (memset together with bitmap)
    //   dinv   @ 12,840,000 :     40,000 B
    //   xs     @ 12,880,000 :  5,120,000 B   (bf16 prescaled x)
    const size_t DEG_OFF  = 12800000;
    const size_t DINV_OFF = 12840000;
    const size_t XS_OFF   = 12880000;
    const size_t NEED_NEW = 18000000;
    const size_t NEED_FB  = 12840000;            // bitmap + dinv (r7-proven size)

    if (ws_size >= NEED_NEW) {
        uint32_t* bitmap = (uint32_t*)ws;
        uint32_t* deg    = (uint32_t*)(ws + DEG_OFF);
        float*    dinv   = (float*)(ws + DINV_OFF);
        uint16_t* xs     = (uint16_t*)(ws + XS_OFF);

        hipMemsetAsync(bitmap, 0, DINV_OFF, stream);               // bitmap+deg
        scatter_deg<<<(E_EDGES + 255) / 256, 256, 0, stream>>>(ei, bitmap, deg);
        scale_cast <<<N_NODES / 4, 256, 0, stream>>>(deg, x, dinv, xs);
        spmm_xs    <<<N_NODES / 4, 256, 0, stream>>>(bitmap, dinv, xs, out);
        gemm_valu  <<<N_NODES / 16, 256, 0, stream>>>(out, w);
    } else if (ws_size >= NEED_FB) {
        uint32_t* bitmap = (uint32_t*)ws;
        float*    dinv   = (float*)(ws + DEG_OFF);                 // 40 KB slot

        hipMemsetAsync(bitmap, 0, DEG_OFF, stream);
        scatter_edges_fb<<<(E_EDGES + 255) / 256, 256, 0, stream>>>(ei, bitmap);
        popc_dinv      <<<N_NODES / 4, 256, 0, stream>>>(bitmap, dinv);
        spmm_bitmap_fb <<<N_NODES / 4, 256, 0, stream>>>(bitmap, dinv, x, out);
        gemm_valu      <<<N_NODES / 16, 256, 0, stream>>>(out, w);
    }
    // else: ws too small for any safe plan — no-op (never observed).
}

// Round 9
// 169.688 us; speedup vs baseline: 1.2171x; 1.2171x over previous
//
#include <hip/hip_runtime.h>
#include <hip/hip_bf16.h>
#include <stdint.h>

// Problem constants (fixed by reference spec; dtypes f32/int32 verified over
// rounds 3-8 — bit-stable outputs; bounds-clamps retained as the safety net)
#define N_NODES   10000
#define D_FEAT    256
#define E_EDGES   320000
#define ROW_WORDS 313     // ceil(10000/32) bitmap words per row
#define ROW_STRIDE 320    // fallback plan: padded words per bitmap row
#define LIST_CAP  1024    // fallback plan: per-wave neighbor list capacity

// Bucketed-CSR build (primary plan)
#define NB    250         // buckets
#define RPB   40          // rows per bucket (250*40 = 10000 exactly)
#define B_CAP 8192        // entries per bucket; mean 5120, sigma ~71 -> 30+ sigma

typedef __attribute__((ext_vector_type(4))) float float4v;  // 4 x f32

__device__ __forceinline__ uint16_t f2bf(float f) {   // RNE, finite inputs
    union { float f; uint32_t u; } v; v.f = f;
    uint32_t r = v.u + 0x7fffu + ((v.u >> 16) & 1u);
    return (uint16_t)(r >> 16);
}
__device__ __forceinline__ float lo16(uint32_t u) {
    union { uint32_t u; float f; } v; v.u = u << 16; return v.f;
}
__device__ __forceinline__ float hi16(uint32_t u) {
    union { uint32_t u; float f; } v; v.u = u & 0xffff0000u; return v.f;
}

// ===========================================================================
// PRIMARY PLAN: bucketed LDS dedup -> CSR  (r8 post-mortem: random global
// atomics were the bottleneck — 68 us of serialized 64B-line scatter. Here
// global atomics touch only 251 cursors; everything else is coalesced.)
// ===========================================================================

// ---------------------------------------------------------------------------
// P1: partition edge endpoints into 250 row-group buckets.
// Entry = (local_row << 14) | col  (local_row < 40, col < 16384).
// LDS-aggregated cursor reservation: 250 global atomics per block (313 blocks).
// ---------------------------------------------------------------------------
__global__ void __launch_bounds__(1024)
fill_buckets(const int* __restrict__ ei, uint32_t* __restrict__ bucketbuf,
             uint32_t* __restrict__ cursors) {
    __shared__ uint32_t hist[NB];
    __shared__ uint32_t base_s[NB];
    int t = threadIdx.x;
    for (int b = t; b < NB; b += 1024) hist[b] = 0;
    __syncthreads();
    int e = blockIdx.x * 1024 + t;
    int b0 = -1, b1 = -1; uint32_t ent0 = 0, ent1 = 0, slot0 = 0, slot1 = 0;
    if (e < E_EDGES) {
        int s = ei[e], d = ei[E_EDGES + e];
        if ((uint32_t)s < N_NODES && (uint32_t)d < N_NODES) {
            b0 = s / RPB; ent0 = ((uint32_t)(s - b0 * RPB) << 14) | (uint32_t)d;
            b1 = d / RPB; ent1 = ((uint32_t)(d - b1 * RPB) << 14) | (uint32_t)s;
            slot0 = atomicAdd(&hist[b0], 1u);
            slot1 = atomicAdd(&hist[b1], 1u);
        }
    }
    __syncthreads();
    for (int b = t; b < NB; b += 1024)
        base_s[b] = hist[b] ? atomicAdd(&cursors[b], hist[b]) : 0u;
    __syncthreads();
    if (b0 >= 0) {
        uint32_t p0 = base_s[b0] + slot0;
        if (p0 < B_CAP) bucketbuf[(size_t)b0 * B_CAP + p0] = ent0;
        uint32_t p1 = base_s[b1] + slot1;
        if (p1 < B_CAP) bucketbuf[(size_t)b1 * B_CAP + p1] = ent1;
    }
}

// ---------------------------------------------------------------------------
// P2: one block per bucket. Entries -> LDS bitmap (exact dedup, cheap LDS
// atomics) -> per-row popc (deg, dinv) -> one global atomicAdd reserves the
// block's CSR segment (rows padded to 4-entry alignment so spmm can uint4-
// load) -> expand bits straight to the global col list. No global bitmap.
// ---------------------------------------------------------------------------
__global__ void __launch_bounds__(1024)
bucket_to_csr(const uint32_t* __restrict__ bucketbuf,
              const uint32_t* __restrict__ cursors,
              uint32_t* __restrict__ gcursor,
              uint32_t* __restrict__ col, uint32_t* __restrict__ row_base,
              uint32_t* __restrict__ row_deg, float* __restrict__ dinv) {
    __shared__ uint32_t bm[RPB * ROW_WORDS];      // 40*313*4 = 50,080 B
    __shared__ uint32_t degs[RPB];
    __shared__ uint32_t rowoff[RPB];
    __shared__ uint32_t segbase;
    int b = blockIdx.x, t = threadIdx.x;
    for (int i = t; i < RPB * ROW_WORDS; i += 1024) bm[i] = 0;
    __syncthreads();
    uint32_t cnt = min(cursors[b], (uint32_t)B_CAP);
    const uint32_t* bb = bucketbuf + (size_t)b * B_CAP;
    for (uint32_t i = t; i < cnt; i += 1024) {
        uint32_t ent = bb[i];
        uint32_t lr = ent >> 14, d = ent & 0x3FFFu;
        atomicOr(&bm[lr * ROW_WORDS + (d >> 5)], 1u << (d & 31));
    }
    __syncthreads();
    int wv = t >> 6, lane = t & 63;               // 16 waves
    for (int r = wv; r < RPB; r += 16) {
        int pop = 0;
        #pragma unroll
        for (int k = 0; k < 5; k++) {
            int w = lane + 64 * k;
            if (w < ROW_WORDS) pop += __popc(bm[r * ROW_WORDS + w]);
        }
        #pragma unroll
        for (int off = 32; off > 0; off >>= 1) pop += __shfl_xor(pop, off, 64);
        if (lane == 0) degs[r] = (uint32_t)pop;
    }
    __syncthreads();
    if (t == 0) {                                  // 40-row serial scan (cheap)
        uint32_t run = 0;
        for (int r = 0; r < RPB; r++) {
            rowoff[r] = run;
            run += (degs[r] + 3u) & ~3u;           // 4-entry align per row
        }
        segbase = atomicAdd(gcursor, run);
    }
    __syncthreads();
    int row0 = b * RPB;
    for (int r = wv; r < RPB; r += 16) {
        int gi = row0 + r;
        uint32_t base = segbase + rowoff[r];
        if (lane == 0) {
            row_base[gi] = base;
            row_deg[gi]  = degs[r];
            dinv[gi]     = 1.0f / sqrtf((float)(degs[r] + 1u));
        }
        // expand set bits -> col[base ...]; lane owns words lane, lane+64, ...
        uint32_t wb[5]; int tot = 0;
        #pragma unroll
        for (int k = 0; k < 5; k++) {
            int w = lane + 64 * k;
            uint32_t v = (w < ROW_WORDS) ? bm[r * ROW_WORDS + w] : 0u;
            wb[k] = v; tot += __popc(v);
        }
        int incl = tot;
        #pragma unroll
        for (int off = 1; off < 64; off <<= 1) {
            int v = __shfl_up(incl, off, 64);
            if (lane >= off) incl += v;
        }
        uint32_t p = base + (uint32_t)(incl - tot);
        #pragma unroll
        for (int k = 0; k < 5; k++) {
            uint32_t bits = wb[k];
            uint32_t cbase = (uint32_t)(lane + 64 * k) << 5;
            while (bits) {
                col[p++] = cbase + (uint32_t)__builtin_ctz(bits);
                bits &= bits - 1;
            }
        }
    }
}

// ---------------------------------------------------------------------------
// P3: xs_i = bf16(dinv_i * x_i) — the 5 MB L2-scale prescaled gather table
// (r8-validated: absmax 0.0039, 6x headroom). One wave per row.
// ---------------------------------------------------------------------------
__global__ void __launch_bounds__(256)
scale_cast(const float* __restrict__ dinv, const float* __restrict__ x,
           uint16_t* __restrict__ xs) {
    int wv = threadIdx.x >> 6, lane = threadIdx.x & 63;
    int i = blockIdx.x * 4 + wv;
    float di = dinv[i];
    float4v v = *(const float4v*)(x + (size_t)i * D_FEAT + lane * 4);
    uint2 o;
    o.x = (uint32_t)f2bf(di * v[0]) | ((uint32_t)f2bf(di * v[1]) << 16);
    o.y = (uint32_t)f2bf(di * v[2]) | ((uint32_t)f2bf(di * v[3]) << 16);
    *(uint2*)(xs + (size_t)i * D_FEAT + lane * 4) = o;
}

// ---------------------------------------------------------------------------
// P4: aggregation over the CSR list. One wave per row, 4 rows/block, no LDS.
// 4 independent accumulator sets -> 4 gathers in flight (r7/r8-proven).
// uint4 col reads are wave-uniform (row bases 4-aligned) -> one line fetch.
// out_i = dinv_i * ( sum_j xs_j + xs_i )   [f32, into d_out]
// ---------------------------------------------------------------------------
__global__ void __launch_bounds__(256)
spmm_csr(const uint32_t* __restrict__ row_base, const uint32_t* __restrict__ row_deg,
         const float* __restrict__ dinv, const uint32_t* __restrict__ col,
         const uint16_t* __restrict__ xs, float* __restrict__ out) {
    int wv = threadIdx.x >> 6, lane = threadIdx.x & 63;
    int i = blockIdx.x * 4 + wv;
    uint32_t base = row_base[i], deg = row_deg[i];
    float di = dinv[i];
    float4v z = {0.f, 0.f, 0.f, 0.f};
    float4v acc0 = z, acc1 = z, acc2 = z, acc3 = z;
    size_t ch = (size_t)lane * 4;
    uint32_t t4 = deg & ~3u;
    for (uint32_t t = 0; t < t4; t += 4) {
        uint4 jv = *(const uint4*)&col[base + t];    // wave-uniform broadcast
        uint2 g0 = *(const uint2*)(xs + (size_t)jv.x * D_FEAT + ch);
        uint2 g1 = *(const uint2*)(xs + (size_t)jv.y * D_FEAT + ch);
        uint2 g2 = *(const uint2*)(xs + (size_t)jv.z * D_FEAT + ch);
        uint2 g3 = *(const uint2*)(xs + (size_t)jv.w * D_FEAT + ch);
        acc0[0] += lo16(g0.x); acc0[1] += hi16(g0.x); acc0[2] += lo16(g0.y); acc0[3] += hi16(g0.y);
        acc1[0] += lo16(g1.x); acc1[1] += hi16(g1.x); acc1[2] += lo16(g1.y); acc1[3] += hi16(g1.y);
        acc2[0] += lo16(g2.x); acc2[1] += hi16(g2.x); acc2[2] += lo16(g2.y); acc2[3] += hi16(g2.y);
        acc3[0] += lo16(g3.x); acc3[1] += hi16(g3.x); acc3[2] += lo16(g3.y); acc3[3] += hi16(g3.y);
    }
    for (uint32_t t = t4; t < deg; t++) {
        uint32_t j = col[base + t];
        uint2 g = *(const uint2*)(xs + (size_t)j * D_FEAT + ch);
        acc0[0] += lo16(g.x); acc0[1] += hi16(g.x); acc0[2] += lo16(g.y); acc0[3] += hi16(g.y);
    }
    uint2 gs = *(const uint2*)(xs + (size_t)i * D_FEAT + ch);   // +I self term
    acc1[0] += lo16(gs.x); acc1[1] += hi16(gs.x); acc1[2] += lo16(gs.y); acc1[3] += hi16(gs.y);
    float4v acc = (acc0 + acc1) + (acc2 + acc3);
    *(float4v*)(out + (size_t)i * D_FEAT + ch) = di * acc;
}

// ===========================================================================
// FALLBACK PLAN (r7-proven, ~12.85 MB): global bitmap + popc + f32 gather
// ===========================================================================

__global__ void scatter_edges_fb(const int* __restrict__ ei,
                                 uint32_t* __restrict__ bitmap) {
    int e = blockIdx.x * blockDim.x + threadIdx.x;
    if (e >= E_EDGES) return;
    int s = ei[e], d = ei[E_EDGES + e];
    if ((uint32_t)s >= N_NODES || (uint32_t)d >= N_NODES) return;
    atomicOr(&bitmap[(size_t)s * ROW_STRIDE + (d >> 5)], 1u << (d & 31));
    atomicOr(&bitmap[(size_t)d * ROW_STRIDE + (s >> 5)], 1u << (s & 31));
}

__global__ void __launch_bounds__(256)
popc_dinv(const uint32_t* __restrict__ bitmap, float* __restrict__ dinv) {
    int wv = threadIdx.x >> 6, lane = threadIdx.x & 63;
    int i = blockIdx.x * 4 + wv;
    const uint32_t* rb = bitmap + (size_t)i * ROW_STRIDE;
    int pop = 0;
    #pragma unroll
    for (int k = 0; k < 5; k++) {
        int w = lane + 64 * k;
        if (w < ROW_WORDS) pop += __popc(rb[w]);
    }
    #pragma unroll
    for (int off = 32; off > 0; off >>= 1) pop += __shfl_xor(pop, off, 64);
    if (lane == 0) dinv[i] = 1.0f / sqrtf((float)(pop + 1));
}

__global__ void __launch_bounds__(256)
spmm_bitmap_fb(const uint32_t* __restrict__ bitmap, const float* __restrict__ dinv,
               const float* __restrict__ xf, float* __restrict__ agg) {
    __shared__ __align__(16) uint32_t lists[4][LIST_CAP];
    int wv = threadIdx.x >> 6, lane = threadIdx.x & 63;
    int i = blockIdx.x * 4 + wv;
    uint32_t* list = lists[wv];
    const uint32_t* rb = bitmap + (size_t)i * ROW_STRIDE;

    uint32_t wbits[5]; int tot = 0;
    #pragma unroll
    for (int k = 0; k < 5; k++) {
        int w = lane + 64 * k;
        uint32_t b = (w < ROW_WORDS) ? rb[w] : 0u;
        wbits[k] = b;
        tot += __popc(b);
    }
    int incl = tot;
    #pragma unroll
    for (int off = 1; off < 64; off <<= 1) {
        int v = __shfl_up(incl, off, 64);
        if (lane >= off) incl += v;
    }
    uint32_t p = (uint32_t)(incl - tot);
    uint32_t deg = (uint32_t)__shfl(incl, 63, 64);
    #pragma unroll
    for (int k = 0; k < 5; k++) {
        uint32_t bits = wbits[k];
        uint32_t base = (uint32_t)(lane + 64 * k) << 5;
        while (bits) {
            if (p < LIST_CAP) list[p] = base + (uint32_t)__builtin_ctz(bits);
            p++;
            bits &= bits - 1;
        }
    }
    if (deg > LIST_CAP) deg = LIST_CAP;

    float di = dinv[i];
    float4v z = {0.f, 0.f, 0.f, 0.f};
    float4v acc0 = z, acc1 = z, acc2 = z, acc3 = z;
    float4v sv = *(const float4v*)(xf + (size_t)i * D_FEAT + lane * 4);
    uint32_t t4 = deg & ~3u;
    for (uint32_t t = 0; t < t4; t += 4) {
        uint4 jv = *(const uint4*)&list[t];
        float d0 = dinv[jv.x], d1 = dinv[jv.y], d2 = dinv[jv.z], d3 = dinv[jv.w];
        float4v v0 = *(const float4v*)(xf + (size_t)jv.x * D_FEAT + lane * 4);
        float4v v1 = *(const float4v*)(xf + (size_t)jv.y * D_FEAT + lane * 4);
        float4v v2 = *(const float4v*)(xf + (size_t)jv.z * D_FEAT + lane * 4);
        float4v v3 = *(const float4v*)(xf + (size_t)jv.w * D_FEAT + lane * 4);
        acc0 += d0 * v0; acc1 += d1 * v1; acc2 += d2 * v2; acc3 += d3 * v3;
    }
    for (uint32_t t = t4; t < deg; t++) {
        uint32_t j = list[t];
        acc0 += dinv[j] * (*(const float4v*)(xf + (size_t)j * D_FEAT + lane * 4));
    }
    float4v acc = (acc0 + acc1) + (acc2 + acc3) + di * sv;
    *(float4v*)(agg + (size_t)i * D_FEAT + lane * 4) = di * acc;
}

// ===========================================================================
// Shared epilogue GEMM: out[band,:] = agg[band,:] @ W, in place on d_out.
// ds_read_b128 A reads (r8); wave-broadcast LDS; coalesced W columns.
// ===========================================================================
__global__ void __launch_bounds__(256)
gemm_valu(float* __restrict__ io, const float* __restrict__ wf) {
    __shared__ __align__(16) float a_lds[16 * D_FEAT];
    int c = threadIdx.x;
    int r0 = blockIdx.x * 16;
    for (int idx = c; idx < 16 * D_FEAT; idx += 256)
        a_lds[idx] = io[(size_t)r0 * D_FEAT + idx];
    __syncthreads();

    float acc[16];
    #pragma unroll
    for (int r = 0; r < 16; r++) acc[r] = 0.f;

    for (int k0 = 0; k0 < D_FEAT; k0 += 4) {
        float w0 = wf[(size_t)(k0 + 0) * D_FEAT + c];
        float w1 = wf[(size_t)(k0 + 1) * D_FEAT + c];
        float w2 = wf[(size_t)(k0 + 2) * D_FEAT + c];
        float w3 = wf[(size_t)(k0 + 3) * D_FEAT + c];
        #pragma unroll
        for (int r = 0; r < 16; r++) {
            float4v av = *(const float4v*)&a_lds[r * D_FEAT + k0];
            acc[r] = fmaf(av[3], w3, fmaf(av[2], w2,
                     fmaf(av[1], w1, fmaf(av[0], w0, acc[r]))));
        }
    }
    #pragma unroll
    for (int r = 0; r < 16; r++)
        io[(size_t)(r0 + r) * D_FEAT + c] = acc[r];
}

// ---------------------------------------------------------------------------
extern "C" void kernel_launch(void* const* d_in, const int* in_sizes, int n_in,
                              void* d_out, int out_size, void* d_ws, size_t ws_size,
                              hipStream_t stream) {
    const float* x  = (const float*)d_in[0];     // f32 [N, 256]
    const int*   ei = (const int*)d_in[1];       // int32 [2, E]
    const float* w  = (const float*)d_in[2];     // f32 [256, 256]
    float* out = (float*)d_out;                  // f32 [N, 256]
    uint8_t* ws = (uint8_t*)d_ws;

    // Primary layout (16.16 MB; r8 proved ws >= 18 MB):
    //   bucketbuf @ 0          : 8,192,000  (250 * 8192 * 4)
    //   cursors   @ 8,192,000  : 2,048      (251 words: 250 cursors + gcursor)
    //   row_base  @ 8,194,048  : 40,000
    //   row_deg   @ 8,234,048  : 40,000
    //   dinv      @ 8,274,048  : 40,000
    //   xs        @ 8,314,048  : 5,120,000  (bf16 prescaled x)
    //   col       @ 13,434,048 : 2,720,000  (<= 640k entries + row padding)
    const size_t CUR_OFF  = 8192000;
    const size_t RB_OFF   = 8194048;
    const size_t RD_OFF   = 8234048;
    const size_t DI_OFF   = 8274048;
    const size_t XS_OFF   = 8314048;
    const size_t COL_OFF  = 13434048;
    const size_t NEED_NEW = 16200000;
    const size_t NEED_FB  = 12840000;

    if (ws_size >= NEED_NEW) {
        uint32_t* bucketbuf = (uint32_t*)ws;
        uint32_t* cursors   = (uint32_t*)(ws + CUR_OFF);
        uint32_t* row_base  = (uint32_t*)(ws + RB_OFF);
        uint32_t* row_deg   = (uint32_t*)(ws + RD_OFF);
        float*    dinv      = (float*)(ws + DI_OFF);
        uint16_t* xs        = (uint16_t*)(ws + XS_OFF);
        uint32_t* col       = (uint32_t*)(ws + COL_OFF);

        hipMemsetAsync(cursors, 0, 2048, stream);    // cursors + gcursor only
        fill_buckets <<<(E_EDGES + 1023) / 1024, 1024, 0, stream>>>(ei, bucketbuf, cursors);
        bucket_to_csr<<<NB, 1024, 0, stream>>>(bucketbuf, cursors, &cursors[NB],
                                               col, row_base, row_deg, dinv);
        scale_cast   <<<N_NODES / 4, 256, 0, stream>>>(dinv, x, xs);
        spmm_csr     <<<N_NODES / 4, 256, 0, stream>>>(row_base, row_deg, dinv, col, xs, out);
        gemm_valu    <<<N_NODES / 16, 256, 0, stream>>>(out, w);
    } else if (ws_size >= NEED_FB) {
        uint32_t* bitmap = (uint32_t*)ws;
        float*    dinv   = (float*)(ws + 12800000);

        hipMemsetAsync(bitmap, 0, 12800000, stream);
        scatter_edges_fb<<<(E_EDGES + 255) / 256, 256, 0, stream>>>(ei, bitmap);
        popc_dinv      <<<N_NODES / 4, 256, 0, stream>>>(bitmap, dinv);
        spmm_bitmap_fb <<<N_NODES / 4, 256, 0, stream>>>(bitmap, dinv, x, out);
        gemm_valu      <<<N_NODES / 16, 256, 0, stream>>>(out, w);
    }
    // else: ws too small for any safe plan — no-op (never observed).
}

// Round 10
// 147.494 us; speedup vs baseline: 1.4003x; 1.1505x over previous
//
#include <hip/hip_runtime.h>
#include <hip/hip_bf16.h>
#include <stdint.h>

// Problem constants (fixed by reference spec; dtypes f32/int32 verified over
// rounds 3-9 — bit-stable outputs; bounds-clamps retained as the safety net)
#define N_NODES   10000
#define D_FEAT    256
#define E_EDGES   320000
#define ROW_WORDS 313     // ceil(10000/32) bitmap words per row
#define ROW_STRIDE 320    // fallback plan: padded words per bitmap row
#define LIST_CAP  1024    // fallback plan: per-wave neighbor list capacity

// Bucketed-CSR build (primary plan, r9-proven)
#define NB    250         // buckets
#define RPB   40          // rows per bucket (250*40 = 10000 exactly)
#define B_CAP 8192        // entries per bucket; mean 5120, sigma ~71 -> 30+ sigma

typedef __attribute__((ext_vector_type(4))) float float4v;   // 4 x f32
typedef _Float16 half8  __attribute__((ext_vector_type(8))); // 8 x f16 (4 VGPR)
typedef _Float16 half4v __attribute__((ext_vector_type(4))); // 4 x f16

__device__ __forceinline__ uint16_t f2bf(float f) {   // RNE, finite inputs
    union { float f; uint32_t u; } v; v.f = f;
    uint32_t r = v.u + 0x7fffu + ((v.u >> 16) & 1u);
    return (uint16_t)(r >> 16);
}
__device__ __forceinline__ float lo16(uint32_t u) {
    union { uint32_t u; float f; } v; v.u = u << 16; return v.f;
}
__device__ __forceinline__ float hi16(uint32_t u) {
    union { uint32_t u; float f; } v; v.u = u & 0xffff0000u; return v.f;
}

// ===========================================================================
// PRIMARY PLAN: bucketed LDS dedup -> CSR -> bf16 gather -> f16 MFMA GEMM
// ===========================================================================

// ---------------------------------------------------------------------------
// P1: partition edge endpoints into 250 row-group buckets (r9-proven).
// ---------------------------------------------------------------------------
__global__ void __launch_bounds__(1024)
fill_buckets(const int* __restrict__ ei, uint32_t* __restrict__ bucketbuf,
             uint32_t* __restrict__ cursors) {
    __shared__ uint32_t hist[NB];
    __shared__ uint32_t base_s[NB];
    int t = threadIdx.x;
    for (int b = t; b < NB; b += 1024) hist[b] = 0;
    __syncthreads();
    int e = blockIdx.x * 1024 + t;
    int b0 = -1, b1 = -1; uint32_t ent0 = 0, ent1 = 0, slot0 = 0, slot1 = 0;
    if (e < E_EDGES) {
        int s = ei[e], d = ei[E_EDGES + e];
        if ((uint32_t)s < N_NODES && (uint32_t)d < N_NODES) {
            b0 = s / RPB; ent0 = ((uint32_t)(s - b0 * RPB) << 14) | (uint32_t)d;
            b1 = d / RPB; ent1 = ((uint32_t)(d - b1 * RPB) << 14) | (uint32_t)s;
            slot0 = atomicAdd(&hist[b0], 1u);
            slot1 = atomicAdd(&hist[b1], 1u);
        }
    }
    __syncthreads();
    for (int b = t; b < NB; b += 1024)
        base_s[b] = hist[b] ? atomicAdd(&cursors[b], hist[b]) : 0u;
    __syncthreads();
    if (b0 >= 0) {
        uint32_t p0 = base_s[b0] + slot0;
        if (p0 < B_CAP) bucketbuf[(size_t)b0 * B_CAP + p0] = ent0;
        uint32_t p1 = base_s[b1] + slot1;
        if (p1 < B_CAP) bucketbuf[(size_t)b1 * B_CAP + p1] = ent1;
    }
}

// ---------------------------------------------------------------------------
// P2: bucket entries -> LDS bitmap dedup -> deg/dinv -> compact global CSR
// (rows 4-entry aligned). One global atomic per block (r9-proven).
// ---------------------------------------------------------------------------
__global__ void __launch_bounds__(1024)
bucket_to_csr(const uint32_t* __restrict__ bucketbuf,
              const uint32_t* __restrict__ cursors,
              uint32_t* __restrict__ gcursor,
              uint32_t* __restrict__ col, uint32_t* __restrict__ row_base,
              uint32_t* __restrict__ row_deg, float* __restrict__ dinv) {
    __shared__ uint32_t bm[RPB * ROW_WORDS];      // 50,080 B
    __shared__ uint32_t degs[RPB];
    __shared__ uint32_t rowoff[RPB];
    __shared__ uint32_t segbase;
    int b = blockIdx.x, t = threadIdx.x;
    for (int i = t; i < RPB * ROW_WORDS; i += 1024) bm[i] = 0;
    __syncthreads();
    uint32_t cnt = min(cursors[b], (uint32_t)B_CAP);
    const uint32_t* bb = bucketbuf + (size_t)b * B_CAP;
    for (uint32_t i = t; i < cnt; i += 1024) {
        uint32_t ent = bb[i];
        uint32_t lr = ent >> 14, d = ent & 0x3FFFu;
        atomicOr(&bm[lr * ROW_WORDS + (d >> 5)], 1u << (d & 31));
    }
    __syncthreads();
    int wv = t >> 6, lane = t & 63;               // 16 waves
    for (int r = wv; r < RPB; r += 16) {
        int pop = 0;
        #pragma unroll
        for (int k = 0; k < 5; k++) {
            int w = lane + 64 * k;
            if (w < ROW_WORDS) pop += __popc(bm[r * ROW_WORDS + w]);
        }
        #pragma unroll
        for (int off = 32; off > 0; off >>= 1) pop += __shfl_xor(pop, off, 64);
        if (lane == 0) degs[r] = (uint32_t)pop;
    }
    __syncthreads();
    if (t == 0) {
        uint32_t run = 0;
        for (int r = 0; r < RPB; r++) {
            rowoff[r] = run;
            run += (degs[r] + 3u) & ~3u;           // 4-entry align per row
        }
        segbase = atomicAdd(gcursor, run);
    }
    __syncthreads();
    int row0 = b * RPB;
    for (int r = wv; r < RPB; r += 16) {
        int gi = row0 + r;
        uint32_t base = segbase + rowoff[r];
        if (lane == 0) {
            row_base[gi] = base;
            row_deg[gi]  = degs[r];
            dinv[gi]     = 1.0f / sqrtf((float)(degs[r] + 1u));
        }
        uint32_t wb[5]; int tot = 0;
        #pragma unroll
        for (int k = 0; k < 5; k++) {
            int w = lane + 64 * k;
            uint32_t v = (w < ROW_WORDS) ? bm[r * ROW_WORDS + w] : 0u;
            wb[k] = v; tot += __popc(v);
        }
        int incl = tot;
        #pragma unroll
        for (int off = 1; off < 64; off <<= 1) {
            int v = __shfl_up(incl, off, 64);
            if (lane >= off) incl += v;
        }
        uint32_t p = base + (uint32_t)(incl - tot);
        #pragma unroll
        for (int k = 0; k < 5; k++) {
            uint32_t bits = wb[k];
            uint32_t cbase = (uint32_t)(lane + 64 * k) << 5;
            while (bits) {
                col[p++] = cbase + (uint32_t)__builtin_ctz(bits);
                bits &= bits - 1;
            }
        }
    }
}

// ---------------------------------------------------------------------------
// P3: xs_i = bf16(dinv_i * x_i)  — 5 MB L2-scale gather table (r8-proven).
// ---------------------------------------------------------------------------
__global__ void __launch_bounds__(256)
scale_cast(const float* __restrict__ dinv, const float* __restrict__ x,
           uint16_t* __restrict__ xs) {
    int wv = threadIdx.x >> 6, lane = threadIdx.x & 63;
    int i = blockIdx.x * 4 + wv;
    float di = dinv[i];
    float4v v = *(const float4v*)(x + (size_t)i * D_FEAT + lane * 4);
    uint2 o;
    o.x = (uint32_t)f2bf(di * v[0]) | ((uint32_t)f2bf(di * v[1]) << 16);
    o.y = (uint32_t)f2bf(di * v[2]) | ((uint32_t)f2bf(di * v[3]) << 16);
    *(uint2*)(xs + (size_t)i * D_FEAT + lane * 4) = o;
}

// ---------------------------------------------------------------------------
// P3b: wT[n][k] = f16(W[k][n]) — B operand for MFMA (128 KB, L2-resident).
// ---------------------------------------------------------------------------
__global__ void __launch_bounds__(256)
wcast(const float* __restrict__ w, _Float16* __restrict__ wt) {
    int k = blockIdx.x, n = threadIdx.x;
    wt[(size_t)n * D_FEAT + k] = (_Float16)w[(size_t)k * D_FEAT + n];
}

// ---------------------------------------------------------------------------
// P4: aggregation over the CSR list -> agg in F16 (GEMM A operand).
// One wave per row, 4 independent gather streams (r7-9 proven).
// agg_i = dinv_i * ( sum_j xs_j + xs_i )
// ---------------------------------------------------------------------------
__global__ void __launch_bounds__(256)
spmm_csr(const uint32_t* __restrict__ row_base, const uint32_t* __restrict__ row_deg,
         const float* __restrict__ dinv, const uint32_t* __restrict__ col,
         const uint16_t* __restrict__ xs, _Float16* __restrict__ aggh) {
    int wv = threadIdx.x >> 6, lane = threadIdx.x & 63;
    int i = blockIdx.x * 4 + wv;
    uint32_t base = row_base[i], deg = row_deg[i];
    float di = dinv[i];
    float4v z = {0.f, 0.f, 0.f, 0.f};
    float4v acc0 = z, acc1 = z, acc2 = z, acc3 = z;
    size_t ch = (size_t)lane * 4;
    uint32_t t4 = deg & ~3u;
    for (uint32_t t = 0; t < t4; t += 4) {
        uint4 jv = *(const uint4*)&col[base + t];    // wave-uniform broadcast
        uint2 g0 = *(const uint2*)(xs + (size_t)jv.x * D_FEAT + ch);
        uint2 g1 = *(const uint2*)(xs + (size_t)jv.y * D_FEAT + ch);
        uint2 g2 = *(const uint2*)(xs + (size_t)jv.z * D_FEAT + ch);
        uint2 g3 = *(const uint2*)(xs + (size_t)jv.w * D_FEAT + ch);
        acc0[0] += lo16(g0.x); acc0[1] += hi16(g0.x); acc0[2] += lo16(g0.y); acc0[3] += hi16(g0.y);
        acc1[0] += lo16(g1.x); acc1[1] += hi16(g1.x); acc1[2] += lo16(g1.y); acc1[3] += hi16(g1.y);
        acc2[0] += lo16(g2.x); acc2[1] += hi16(g2.x); acc2[2] += lo16(g2.y); acc2[3] += hi16(g2.y);
        acc3[0] += lo16(g3.x); acc3[1] += hi16(g3.x); acc3[2] += lo16(g3.y); acc3[3] += hi16(g3.y);
    }
    for (uint32_t t = t4; t < deg; t++) {
        uint32_t j = col[base + t];
        uint2 g = *(const uint2*)(xs + (size_t)j * D_FEAT + ch);
        acc0[0] += lo16(g.x); acc0[1] += hi16(g.x); acc0[2] += lo16(g.y); acc0[3] += hi16(g.y);
    }
    uint2 gs = *(const uint2*)(xs + (size_t)i * D_FEAT + ch);   // +I self term
    acc1[0] += lo16(gs.x); acc1[1] += hi16(gs.x); acc1[2] += lo16(gs.y); acc1[3] += hi16(gs.y);
    float4v acc = (acc0 + acc1) + (acc2 + acc3);
    half4v o = { (_Float16)(di * acc[0]), (_Float16)(di * acc[1]),
                 (_Float16)(di * acc[2]), (_Float16)(di * acc[3]) };
    *(half4v*)(aggh + (size_t)i * D_FEAT + ch) = o;
}

// ---------------------------------------------------------------------------
// P5: out = aggh @ W via MFMA f32_16x16x32_f16 (r9 gemm_valu was LDS-issue-
// bound at 57 us: 1024 ds_read_b128/thread feeding 4 FMAs each).
// One wave per 16x16 tile; 8 MFMAs over K=256. Layouts:
//   A[m=lane&15][k=quad*8+j]; B[k=quad*8+j][n=lane&15] from wT rows;
//   C/D col=lane&15, row=quad*4+reg  [m89/m91 verified].
// grid (625, 4) x 256 thr: wave w covers col-tile blockIdx.y*4+w.
// ---------------------------------------------------------------------------
__global__ void __launch_bounds__(256)
gemm_mfma(const _Float16* __restrict__ aggh, const _Float16* __restrict__ wt,
          float* __restrict__ out) {
    int t = threadIdx.x;
    int wv = t >> 6, lane = t & 63;
    int quad = lane >> 4, r = lane & 15;
    int bx = blockIdx.x;                     // row tile (16 rows)
    int ct = blockIdx.y * 4 + wv;            // col tile (16 cols)

    const _Float16* pa = aggh + (size_t)(bx * 16 + r) * D_FEAT + quad * 8;
    const _Float16* pb = wt   + (size_t)(ct * 16 + r) * D_FEAT + quad * 8;

    float4v acc = {0.f, 0.f, 0.f, 0.f};
    #pragma unroll
    for (int kk = 0; kk < D_FEAT; kk += 32) {
        half8 a = *(const half8*)(pa + kk);
        half8 b = *(const half8*)(pb + kk);
        acc = __builtin_amdgcn_mfma_f32_16x16x32_f16(a, b, acc, 0, 0, 0);
    }
    int mbase = bx * 16 + quad * 4;
    int colg  = ct * 16 + r;
    #pragma unroll
    for (int u = 0; u < 4; u++)
        out[(size_t)(mbase + u) * D_FEAT + colg] = acc[u];
}

// ===========================================================================
// FALLBACK PLAN (r7-proven, ~12.85 MB): global bitmap + popc + f32 gather
// ===========================================================================

__global__ void scatter_edges_fb(const int* __restrict__ ei,
                                 uint32_t* __restrict__ bitmap) {
    int e = blockIdx.x * blockDim.x + threadIdx.x;
    if (e >= E_EDGES) return;
    int s = ei[e], d = ei[E_EDGES + e];
    if ((uint32_t)s >= N_NODES || (uint32_t)d >= N_NODES) return;
    atomicOr(&bitmap[(size_t)s * ROW_STRIDE + (d >> 5)], 1u << (d & 31));
    atomicOr(&bitmap[(size_t)d * ROW_STRIDE + (s >> 5)], 1u << (s & 31));
}

__global__ void __launch_bounds__(256)
popc_dinv(const uint32_t* __restrict__ bitmap, float* __restrict__ dinv) {
    int wv = threadIdx.x >> 6, lane = threadIdx.x & 63;
    int i = blockIdx.x * 4 + wv;
    const uint32_t* rb = bitmap + (size_t)i * ROW_STRIDE;
    int pop = 0;
    #pragma unroll
    for (int k = 0; k < 5; k++) {
        int w = lane + 64 * k;
        if (w < ROW_WORDS) pop += __popc(rb[w]);
    }
    #pragma unroll
    for (int off = 32; off > 0; off >>= 1) pop += __shfl_xor(pop, off, 64);
    if (lane == 0) dinv[i] = 1.0f / sqrtf((float)(pop + 1));
}

__global__ void __launch_bounds__(256)
spmm_bitmap_fb(const uint32_t* __restrict__ bitmap, const float* __restrict__ dinv,
               const float* __restrict__ xf, float* __restrict__ agg) {
    __shared__ __align__(16) uint32_t lists[4][LIST_CAP];
    int wv = threadIdx.x >> 6, lane = threadIdx.x & 63;
    int i = blockIdx.x * 4 + wv;
    uint32_t* list = lists[wv];
    const uint32_t* rb = bitmap + (size_t)i * ROW_STRIDE;

    uint32_t wbits[5]; int tot = 0;
    #pragma unroll
    for (int k = 0; k < 5; k++) {
        int w = lane + 64 * k;
        uint32_t b = (w < ROW_WORDS) ? rb[w] : 0u;
        wbits[k] = b;
        tot += __popc(b);
    }
    int incl = tot;
    #pragma unroll
    for (int off = 1; off < 64; off <<= 1) {
        int v = __shfl_up(incl, off, 64);
        if (lane >= off) incl += v;
    }
    uint32_t p = (uint32_t)(incl - tot);
    uint32_t deg = (uint32_t)__shfl(incl, 63, 64);
    #pragma unroll
    for (int k = 0; k < 5; k++) {
        uint32_t bits = wbits[k];
        uint32_t base = (uint32_t)(lane + 64 * k) << 5;
        while (bits) {
            if (p < LIST_CAP) list[p] = base + (uint32_t)__builtin_ctz(bits);
            p++;
            bits &= bits - 1;
        }
    }
    if (deg > LIST_CAP) deg = LIST_CAP;

    float di = dinv[i];
    float4v z = {0.f, 0.f, 0.f, 0.f};
    float4v acc0 = z, acc1 = z, acc2 = z, acc3 = z;
    float4v sv = *(const float4v*)(xf + (size_t)i * D_FEAT + lane * 4);
    uint32_t t4 = deg & ~3u;
    for (uint32_t t = 0; t < t4; t += 4) {
        uint4 jv = *(const uint4*)&list[t];
        float d0 = dinv[jv.x], d1 = dinv[jv.y], d2 = dinv[jv.z], d3 = dinv[jv.w];
        float4v v0 = *(const float4v*)(xf + (size_t)jv.x * D_FEAT + lane * 4);
        float4v v1 = *(const float4v*)(xf + (size_t)jv.y * D_FEAT + lane * 4);
        float4v v2 = *(const float4v*)(xf + (size_t)jv.z * D_FEAT + lane * 4);
        float4v v3 = *(const float4v*)(xf + (size_t)jv.w * D_FEAT + lane * 4);
        acc0 += d0 * v0; acc1 += d1 * v1; acc2 += d2 * v2; acc3 += d3 * v3;
    }
    for (uint32_t t = t4; t < deg; t++) {
        uint32_t j = list[t];
        acc0 += dinv[j] * (*(const float4v*)(xf + (size_t)j * D_FEAT + lane * 4));
    }
    float4v acc = (acc0 + acc1) + (acc2 + acc3) + di * sv;
    *(float4v*)(agg + (size_t)i * D_FEAT + lane * 4) = di * acc;
}

// Fallback epilogue GEMM (in place on d_out) — r9-proven VALU version.
__global__ void __launch_bounds__(256)
gemm_valu(float* __restrict__ io, const float* __restrict__ wf) {
    __shared__ __align__(16) float a_lds[16 * D_FEAT];
    int c = threadIdx.x;
    int r0 = blockIdx.x * 16;
    for (int idx = c; idx < 16 * D_FEAT; idx += 256)
        a_lds[idx] = io[(size_t)r0 * D_FEAT + idx];
    __syncthreads();
    float acc[16];
    #pragma unroll
    for (int r = 0; r < 16; r++) acc[r] = 0.f;
    for (int k0 = 0; k0 < D_FEAT; k0 += 4) {
        float w0 = wf[(size_t)(k0 + 0) * D_FEAT + c];
        float w1 = wf[(size_t)(k0 + 1) * D_FEAT + c];
        float w2 = wf[(size_t)(k0 + 2) * D_FEAT + c];
        float w3 = wf[(size_t)(k0 + 3) * D_FEAT + c];
        #pragma unroll
        for (int r = 0; r < 16; r++) {
            float4v av = *(const float4v*)&a_lds[r * D_FEAT + k0];
            acc[r] = fmaf(av[3], w3, fmaf(av[2], w2,
                     fmaf(av[1], w1, fmaf(av[0], w0, acc[r]))));
        }
    }
    #pragma unroll
    for (int r = 0; r < 16; r++)
        io[(size_t)(r0 + r) * D_FEAT + c] = acc[r];
}

// ---------------------------------------------------------------------------
extern "C" void kernel_launch(void* const* d_in, const int* in_sizes, int n_in,
                              void* d_out, int out_size, void* d_ws, size_t ws_size,
                              hipStream_t stream) {
    const float* x  = (const float*)d_in[0];     // f32 [N, 256]
    const int*   ei = (const int*)d_in[1];       // int32 [2, E]
    const float* w  = (const float*)d_in[2];     // f32 [256, 256]
    float* out = (float*)d_out;                  // f32 [N, 256]
    uint8_t* ws = (uint8_t*)d_ws;

    // Primary layout (16.29 MB; ws >= 18 MB proven by r8/r9):
    //   bucketbuf @ 0          : 8,192,000   -- dead after bucket_to_csr;
    //   aggh      @ 0          : 5,120,000      REUSED as f16 agg (A operand)
    //   cursors   @ 8,192,000  : 2,048       (250 cursors + gcursor)
    //   row_base  @ 8,194,048  : 40,000
    //   row_deg   @ 8,234,048  : 40,000
    //   dinv      @ 8,274,048  : 40,000
    //   xs        @ 8,314,048  : 5,120,000   (bf16 prescaled x)
    //   col       @ 13,434,048 : 2,720,000
    //   wT(f16)   @ 16,154,048 : 131,072
    const size_t CUR_OFF  = 8192000;
    const size_t RB_OFF   = 8194048;
    const size_t RD_OFF   = 8234048;
    const size_t DI_OFF   = 8274048;
    const size_t XS_OFF   = 8314048;
    const size_t COL_OFF  = 13434048;
    const size_t WT_OFF   = 16154048;
    const size_t NEED_NEW = 16285120;
    const size_t NEED_FB  = 12840000;

    if (ws_size >= NEED_NEW) {
        uint32_t* bucketbuf = (uint32_t*)ws;
        _Float16* aggh      = (_Float16*)ws;         // reuse (sequential kernels)
        uint32_t* cursors   = (uint32_t*)(ws + CUR_OFF);
        uint32_t* row_base  = (uint32_t*)(ws + RB_OFF);
        uint32_t* row_deg   = (uint32_t*)(ws + RD_OFF);
        float*    dinv      = (float*)(ws + DI_OFF);
        uint16_t* xs        = (uint16_t*)(ws + XS_OFF);
        uint32_t* col       = (uint32_t*)(ws + COL_OFF);
        _Float16* wt        = (_Float16*)(ws + WT_OFF);

        hipMemsetAsync(cursors, 0, 2048, stream);    // cursors + gcursor only
        fill_buckets <<<(E_EDGES + 1023) / 1024, 1024, 0, stream>>>(ei, bucketbuf, cursors);
        bucket_to_csr<<<NB, 1024, 0, stream>>>(bucketbuf, cursors, &cursors[NB],
                                               col, row_base, row_deg, dinv);
        wcast        <<<D_FEAT, D_FEAT, 0, stream>>>(w, wt);
        scale_cast   <<<N_NODES / 4, 256, 0, stream>>>(dinv, x, xs);
        spmm_csr     <<<N_NODES / 4, 256, 0, stream>>>(row_base, row_deg, dinv, col, xs, aggh);
        gemm_mfma    <<<dim3(N_NODES / 16, 4), 256, 0, stream>>>(aggh, wt, out);
    } else if (ws_size >= NEED_FB) {
        uint32_t* bitmap = (uint32_t*)ws;
        float*    dinv   = (float*)(ws + 12800000);

        hipMemsetAsync(bitmap, 0, 12800000, stream);
        scatter_edges_fb<<<(E_EDGES + 255) / 256, 256, 0, stream>>>(ei, bitmap);
        popc_dinv      <<<N_NODES / 4, 256, 0, stream>>>(bitmap, dinv);
        spmm_bitmap_fb <<<N_NODES / 4, 256, 0, stream>>>(bitmap, dinv, x, out);
        gemm_valu      <<<N_NODES / 16, 256, 0, stream>>>(out, w);
    }
    // else: ws too small for any safe plan — no-op (never observed).
}